// Round 6
// baseline (1229.578 us; speedup 1.0000x reference)
//
#include <hip/hip_runtime.h>
#include <math.h>

#define NTOK 4096
#define DM 1024
#define TSEQ 2048
#define NH 16
#define NKV 4
#define HDIM 64
#define NE 8
#define NFF 2048
#define QKVN 1536

typedef float f4v __attribute__((ext_vector_type(4)));
typedef short b8v __attribute__((ext_vector_type(8)));
typedef unsigned short u16;

__device__ __forceinline__ float silu_f(float v) { return v / (1.0f + expf(-v)); }

__device__ __forceinline__ u16 f2b(float f) {  // RNE
    union { float f; unsigned u; } x{f};
    unsigned r = (x.u + 0x7FFFu + ((x.u >> 16) & 1u)) >> 16;
    return (u16)r;
}
__device__ __forceinline__ u16 f2bt(float f) {  // truncate
    union { float f; unsigned u; } x{f};
    return (u16)(x.u >> 16);
}
__device__ __forceinline__ float b2f(u16 b) {
    union { unsigned u; float f; } x;
    x.u = ((unsigned)b) << 16;
    return x.f;
}

// async global->LDS, 16B per lane; LDS dest = wave-uniform base + lane*16
__device__ __forceinline__ void gload16(const void* g, void* l) {
    typedef __attribute__((address_space(1))) const void gv;
    typedef __attribute__((address_space(3))) void lv;
    __builtin_amdgcn_global_load_lds((gv*)g, (lv*)l, 16, 0, 0);
}

// ---------------- RMSNorm, MODE 0: hi/lo split; MODE 1: f32 + plain bf16 ----
template <int MODE>
__global__ __launch_bounds__(256) void rmsnorm2_k(const float* __restrict__ x,
                                                  const float* __restrict__ w,
                                                  u16* __restrict__ oh, u16* __restrict__ ol,
                                                  float* __restrict__ of) {
    int row = blockIdx.x;
    int tid = threadIdx.x;
    const float4 v = ((const float4*)(x + (size_t)row * DM))[tid];
    float ss = v.x * v.x + v.y * v.y + v.z * v.z + v.w * v.w;
    for (int off = 32; off; off >>= 1) ss += __shfl_down(ss, off);
    __shared__ float red[4];
    if ((tid & 63) == 0) red[tid >> 6] = ss;
    __syncthreads();
    float tot = red[0] + red[1] + red[2] + red[3];
    float inv = rsqrtf(tot * (1.0f / DM) + 1e-6f);
    const float4 wv = ((const float4*)w)[tid];
    float o[4];
    o[0] = v.x * inv * wv.x; o[1] = v.y * inv * wv.y;
    o[2] = v.z * inv * wv.z; o[3] = v.w * inv * wv.w;
    if (MODE == 1) {
        float4 f; f.x = o[0]; f.y = o[1]; f.z = o[2]; f.w = o[3];
        ((float4*)(of + (size_t)row * DM))[tid] = f;
        ushort4 hb;
        hb.x = f2b(o[0]); hb.y = f2b(o[1]); hb.z = f2b(o[2]); hb.w = f2b(o[3]);
        ((ushort4*)(oh + (size_t)row * DM))[tid] = hb;
    } else {
        ushort4 hb, lb;
#pragma unroll
        for (int i = 0; i < 4; ++i) {
            u16 h = f2b(o[i]);
            u16 l = f2b(o[i] - b2f(h));
            ((u16*)&hb)[i] = h;
            ((u16*)&lb)[i] = l;
        }
        ((ushort4*)(oh + (size_t)row * DM))[tid] = hb;
        ((ushort4*)(ol + (size_t)row * DM))[tid] = lb;
    }
}

// ---------------- RoPE cos/sin table: tab[t*64 + j*2] = cos, +1 = sin ----------------
__global__ __launch_bounds__(256) void ropetab_k(float* __restrict__ tab) {
    int idx = blockIdx.x * 256 + threadIdx.x;
    if (idx >= TSEQ * 32) return;
    int t = idx >> 5, j = idx & 31;
    float inv = expf(-(float)j * (0.03125f * logf(10000.0f)));
    float s, c;
    sincosf((float)t * inv, &s, &c);
    tab[t * 64 + j * 2] = c;
    tab[t * 64 + j * 2 + 1] = s;
}

// ---------------- fused RoPE + hi/lo split: qkv f32 cols [colbase, colbase+cols) ------
__global__ __launch_bounds__(256) void rope_split_k(const float* __restrict__ qkv,
                                                    const float* __restrict__ tab,
                                                    int colbase, int cols,
                                                    u16* __restrict__ oh, u16* __restrict__ ol) {
    int idx = blockIdx.x * 256 + threadIdx.x;  // octet index
    int cpr = cols >> 3;
    int row = idx / cpr;
    int cc = (idx - row * cpr) << 3;
    const float* p = qkv + (size_t)row * QKVN + colbase + cc;
    const float4 a = *(const float4*)p;
    const float4 b = *(const float4*)(p + 4);
    float vv[8] = {a.x, a.y, a.z, a.w, b.x, b.y, b.z, b.w};
    int tpos = row & (TSEQ - 1);
    const float* tb = tab + tpos * 64 + ((cc & 63) >> 1) * 2;
    float ov[8];
#pragma unroll
    for (int q = 0; q < 4; ++q) {
        float c = tb[q * 2], s = tb[q * 2 + 1];
        float x0 = vv[2 * q], x1 = vv[2 * q + 1];
        ov[2 * q] = x0 * c - x1 * s;
        ov[2 * q + 1] = x0 * s + x1 * c;
    }
    ushort4 h0, h1, l0, l1;
#pragma unroll
    for (int i = 0; i < 8; ++i) {
        u16 h = f2b(ov[i]);
        u16 l = f2b(ov[i] - b2f(h));
        if (i < 4) { ((u16*)&h0)[i] = h; ((u16*)&l0)[i] = l; }
        else       { ((u16*)&h1)[i - 4] = h; ((u16*)&l1)[i - 4] = l; }
    }
    u16* po = oh + (size_t)row * cols + cc;
    u16* pl = ol + (size_t)row * cols + cc;
    *(ushort4*)po = h0; *(ushort4*)(po + 4) = h1;
    *(ushort4*)pl = l0; *(ushort4*)(pl + 4) = l1;
}

// ---------------- V transpose + split ----------------
__global__ __launch_bounds__(256) void vtrans_k(const float* __restrict__ qkv,
                                                u16* __restrict__ oh, u16* __restrict__ ol) {
    __shared__ float tl[32][33];
    int c0 = blockIdx.x << 5;
    int r0 = blockIdx.y << 5;
    int lr = threadIdx.x >> 3, lc = (threadIdx.x & 7) << 2;
    const float4 v = *(const float4*)&qkv[(size_t)(r0 + lr) * QKVN + 1280 + c0 + lc];
    tl[lr][lc] = v.x; tl[lr][lc + 1] = v.y; tl[lr][lc + 2] = v.z; tl[lr][lc + 3] = v.w;
    __syncthreads();
    int b = r0 >> 11;
    size_t obase = ((size_t)(b * 256 + c0 + lr)) * TSEQ + (r0 & 2047) + lc;
    ushort4 h4, l4;
#pragma unroll
    for (int i = 0; i < 4; ++i) {
        float f = tl[lc + i][lr];
        u16 h = f2b(f);
        u16 l = f2b(f - b2f(h));
        ((u16*)&h4)[i] = h; ((u16*)&l4)[i] = l;
    }
    *(ushort4*)&oh[obase] = h4;
    *(ushort4*)&ol[obase] = l4;
}

// ---------------- weight transpose + split cast ----------------
__global__ __launch_bounds__(256) void tcast2_k(const float* __restrict__ in,
                                                u16* __restrict__ oh, u16* __restrict__ ol,
                                                int R, int C) {
    __shared__ float tl[32][33];
    int r0 = blockIdx.y << 5, c0 = blockIdx.x << 5;
    int lr = threadIdx.x >> 3, lc = (threadIdx.x & 7) << 2;
    const float4 v = *(const float4*)&in[(size_t)(r0 + lr) * C + c0 + lc];
    tl[lr][lc] = v.x; tl[lr][lc + 1] = v.y; tl[lr][lc + 2] = v.z; tl[lr][lc + 3] = v.w;
    __syncthreads();
    ushort4 h4, l4;
#pragma unroll
    for (int i = 0; i < 4; ++i) {
        float f = tl[lc + i][lr];
        u16 h = f2b(f);
        u16 l = f2b(f - b2f(h));
        ((u16*)&h4)[i] = h; ((u16*)&l4)[i] = l;
    }
    size_t ob = (size_t)(c0 + lr) * R + r0 + lc;
    *(ushort4*)&oh[ob] = h4;
    *(ushort4*)&ol[ob] = l4;
}

// ---------------- plain weight transpose + bf16 cast (MoE weights) ----------------
__global__ __launch_bounds__(256) void tcast_k(const float* __restrict__ in,
                                               u16* __restrict__ out, int R, int C) {
    size_t boff = (size_t)blockIdx.z * R * C;
    in += boff; out += boff;
    __shared__ float tl[32][33];
    int r0 = blockIdx.y << 5, c0 = blockIdx.x << 5;
    int lr = threadIdx.x >> 3, lc = (threadIdx.x & 7) << 2;
    const float4 v = *(const float4*)&in[(size_t)(r0 + lr) * C + c0 + lc];
    tl[lr][lc] = v.x; tl[lr][lc + 1] = v.y; tl[lr][lc + 2] = v.z; tl[lr][lc + 3] = v.w;
    __syncthreads();
    ushort4 o;
    o.x = f2b(tl[lc + 0][lr]); o.y = f2b(tl[lc + 1][lr]);
    o.z = f2b(tl[lc + 2][lr]); o.w = f2b(tl[lc + 3][lr]);
    *(ushort4*)&out[(size_t)(c0 + lr) * R + r0 + lc] = o;
}

// ---------------- split-bf16 MFMA GEMM with global_load_lds staging ----------------
// LDS linear [128][32] u16 per matrix; XOR swizzle key(row)=(row&3)^((row>>2)&3)
// applied to SOURCE chunk (stage) and READ chunk (frag) — both-sides (rule #21).
template <int EPI>  // 0 plain f32, 2 + residual R
__global__ __launch_bounds__(256) void sgemm_k(const u16* __restrict__ Ah,
                                               const u16* __restrict__ Al,
                                               const u16* __restrict__ Bh,
                                               const u16* __restrict__ Bl,
                                               const float* __restrict__ Rr,
                                               float* __restrict__ C,
                                               int M, int N, int K) {
    __shared__ u16 Ash[128 * 32], Asl[128 * 32], Bsh[128 * 32], Bsl[128 * 32];
    int t = threadIdx.x;
    int l = t & 63, w = t >> 6;
    int wr = w >> 1, wc = w & 1;
    int lx = l & 15, lg = l >> 4;
    int n0 = blockIdx.x * 128, m0 = blockIdx.y * 128;
    int srow = t >> 2;
    int cs = (t & 3) ^ ((srow & 3) ^ ((t >> 4) & 3));  // swizzled source chunk
    const u16 *agh[2], *agl[2], *bgh[2], *bgl[2];
#pragma unroll
    for (int i = 0; i < 2; ++i) {
        size_t ao = (size_t)(m0 + i * 64 + srow) * K + cs * 8;
        size_t bo = (size_t)(n0 + i * 64 + srow) * K + cs * 8;
        agh[i] = Ah + ao; agl[i] = Al + ao;
        bgh[i] = Bh + bo; bgl[i] = Bl + bo;
    }
    f4v acc[4][4];
#pragma unroll
    for (int m = 0; m < 4; ++m)
#pragma unroll
        for (int n = 0; n < 4; ++n) acc[m][n] = (f4v)0.0f;
    int keyr = (lx & 3) ^ ((lx >> 2) & 3);
    int chb = (lg ^ keyr) << 4;  // chunk byte offset
    int aoff[4], boff[4];
#pragma unroll
    for (int m = 0; m < 4; ++m) aoff[m] = ((wr * 64 + m * 16 + lx) << 6) + chb;
#pragma unroll
    for (int n = 0; n < 4; ++n) boff[n] = ((wc * 64 + n * 16 + lx) << 6) + chb;
    int wb = w * 1024;
    for (int k0 = 0; k0 < K; k0 += 32) {
        __syncthreads();
        gload16(agh[0] + k0, (char*)Ash + wb);
        gload16(agh[1] + k0, (char*)Ash + wb + 4096);
        gload16(agl[0] + k0, (char*)Asl + wb);
        gload16(agl[1] + k0, (char*)Asl + wb + 4096);
        gload16(bgh[0] + k0, (char*)Bsh + wb);
        gload16(bgh[1] + k0, (char*)Bsh + wb + 4096);
        gload16(bgl[0] + k0, (char*)Bsl + wb);
        gload16(bgl[1] + k0, (char*)Bsl + wb + 4096);
        __syncthreads();
        b8v afh[4], afl[4], bfh[4], bfl[4];
#pragma unroll
        for (int m = 0; m < 4; ++m) {
            afh[m] = *(const b8v*)((const char*)Ash + aoff[m]);
            afl[m] = *(const b8v*)((const char*)Asl + aoff[m]);
        }
#pragma unroll
        for (int n = 0; n < 4; ++n) {
            bfh[n] = *(const b8v*)((const char*)Bsh + boff[n]);
            bfl[n] = *(const b8v*)((const char*)Bsl + boff[n]);
        }
#pragma unroll
        for (int m = 0; m < 4; ++m)
#pragma unroll
            for (int n = 0; n < 4; ++n) {
                acc[m][n] = __builtin_amdgcn_mfma_f32_16x16x32_bf16(afl[m], bfh[n], acc[m][n], 0, 0, 0);
                acc[m][n] = __builtin_amdgcn_mfma_f32_16x16x32_bf16(afh[m], bfl[n], acc[m][n], 0, 0, 0);
                acc[m][n] = __builtin_amdgcn_mfma_f32_16x16x32_bf16(afh[m], bfh[n], acc[m][n], 0, 0, 0);
            }
    }
#pragma unroll
    for (int m = 0; m < 4; ++m) {
        int r0l = m0 + wr * 64 + m * 16 + ((l >> 4) << 2);
#pragma unroll
        for (int n = 0; n < 4; ++n) {
            int col = n0 + wc * 64 + n * 16 + (l & 15);
            f4v c = acc[m][n];
#pragma unroll
            for (int j = 0; j < 4; ++j) {
                size_t idx = (size_t)(r0l + j) * N + col;
                float v = c[j];
                if (EPI == 2) v += Rr[idx];
                C[idx] = v;
            }
        }
    }
}

// ---------------- split-bf16 MFMA flash attention v3 ----------------
// grid (32, 32): heavy q-tiles first (qt = 31-bx) -> 1024 blocks, 16 waves/CU.
// Barrier-free across waves; P LDS ordered by wave-local fence; trunc P split;
// epilogue writes ao hi/lo splits directly (Wo GEMM input).
__global__ __launch_bounds__(256) void mattn_k(const u16* __restrict__ qh, const u16* __restrict__ ql,
                                               const u16* __restrict__ kh, const u16* __restrict__ kl,
                                               const u16* __restrict__ vth, const u16* __restrict__ vtl,
                                               u16* __restrict__ aoh, u16* __restrict__ aol) {
    __shared__ short plds[4][2][16][72];
    int t = threadIdx.x, l = t & 63, w = t >> 6;
    int bh = blockIdx.y, b = bh >> 4, h = bh & 15, kvh = h >> 2;
    size_t bT = (size_t)b * TSEQ;
    int lx = l & 15, lg = l >> 4;
    int qt = 31 - blockIdx.x;
    int q0 = qt * 64;
    b8v qfh[2], qfl[2];
    {
        size_t qo = (bT + q0 + w * 16 + lx) * DM + h * 64 + lg * 8;
        qfh[0] = *(const b8v*)(qh + qo);
        qfh[1] = *(const b8v*)(qh + qo + 32);
        qfl[0] = *(const b8v*)(ql + qo);
        qfl[1] = *(const b8v*)(ql + qo + 32);
    }
    f4v acc[4];
#pragma unroll
    for (int ht = 0; ht < 4; ++ht) acc[ht] = (f4v)0.0f;
    float l_r[4] = {0.0f, 0.0f, 0.0f, 0.0f};
    int qg[4];
#pragma unroll
    for (int r = 0; r < 4; ++r) qg[r] = q0 + w * 16 + lg * 4 + r;
    int ntile = qt + 1;
    for (int kt = 0; kt < ntile; ++kt) {
        int kv0 = kt << 6;
        f4v s[4];
#pragma unroll
        for (int st = 0; st < 4; ++st) {
            size_t ko = (bT + kv0 + st * 16 + lx) * 256 + kvh * 64 + lg * 8;
            b8v kf0h = *(const b8v*)(kh + ko);
            b8v kf1h = *(const b8v*)(kh + ko + 32);
            b8v kf0l = *(const b8v*)(kl + ko);
            b8v kf1l = *(const b8v*)(kl + ko + 32);
            f4v ss = (f4v)0.0f;
            ss = __builtin_amdgcn_mfma_f32_16x16x32_bf16(qfl[0], kf0h, ss, 0, 0, 0);
            ss = __builtin_amdgcn_mfma_f32_16x16x32_bf16(qfh[0], kf0l, ss, 0, 0, 0);
            ss = __builtin_amdgcn_mfma_f32_16x16x32_bf16(qfh[0], kf0h, ss, 0, 0, 0);
            ss = __builtin_amdgcn_mfma_f32_16x16x32_bf16(qfl[1], kf1h, ss, 0, 0, 0);
            ss = __builtin_amdgcn_mfma_f32_16x16x32_bf16(qfh[1], kf1l, ss, 0, 0, 0);
            ss = __builtin_amdgcn_mfma_f32_16x16x32_bf16(qfh[1], kf1h, ss, 0, 0, 0);
            s[st] = ss;
        }
        // issue V loads early; latency hides under softmax VALU
        b8v vh0[4], vh1[4], vl0[4], vl1[4];
#pragma unroll
        for (int ht = 0; ht < 4; ++ht) {
            size_t vo = ((size_t)(b * 4 + kvh) * 64 + ht * 16 + lx) * TSEQ + kv0 + lg * 8;
            vh0[ht] = *(const b8v*)(vth + vo);
            vh1[ht] = *(const b8v*)(vth + vo + 32);
            vl0[ht] = *(const b8v*)(vtl + vo);
            vl1[ht] = *(const b8v*)(vtl + vo + 32);
        }
        // softmax, m == 0 (scores bounded; clamp for safety); trunc split for P
#pragma unroll
        for (int st = 0; st < 4; ++st)
#pragma unroll
            for (int r = 0; r < 4; ++r) {
                float v = s[st][r] * 0.125f;
                float p = (kv0 + st * 16 + lx > qg[r]) ? 0.0f : __expf(fminf(v, 60.0f));
                l_r[r] += p;
                u16 ph = f2bt(p);
                u16 pl = f2bt(p - b2f(ph));
                plds[w][0][lg * 4 + r][st * 16 + lx] = (short)ph;
                plds[w][1][lg * 4 + r][st * 16 + lx] = (short)pl;
            }
        __threadfence_block();
        __builtin_amdgcn_sched_barrier(0);
        b8v pf0h = *(const b8v*)&plds[w][0][lx][lg * 8];
        b8v pf1h = *(const b8v*)&plds[w][0][lx][32 + lg * 8];
        b8v pf0l = *(const b8v*)&plds[w][1][lx][lg * 8];
        b8v pf1l = *(const b8v*)&plds[w][1][lx][32 + lg * 8];
        __builtin_amdgcn_sched_barrier(0);
#pragma unroll
        for (int ht = 0; ht < 4; ++ht) {
            acc[ht] = __builtin_amdgcn_mfma_f32_16x16x32_bf16(pf0l, vh0[ht], acc[ht], 0, 0, 0);
            acc[ht] = __builtin_amdgcn_mfma_f32_16x16x32_bf16(pf0h, vl0[ht], acc[ht], 0, 0, 0);
            acc[ht] = __builtin_amdgcn_mfma_f32_16x16x32_bf16(pf0h, vh0[ht], acc[ht], 0, 0, 0);
            acc[ht] = __builtin_amdgcn_mfma_f32_16x16x32_bf16(pf1l, vh1[ht], acc[ht], 0, 0, 0);
            acc[ht] = __builtin_amdgcn_mfma_f32_16x16x32_bf16(pf1h, vl1[ht], acc[ht], 0, 0, 0);
            acc[ht] = __builtin_amdgcn_mfma_f32_16x16x32_bf16(pf1h, vh1[ht], acc[ht], 0, 0, 0);
        }
    }
    // epilogue: reduce row sums, write O as hi/lo split (feeds Wo GEMM)
#pragma unroll
    for (int r = 0; r < 4; ++r) {
        float rs = l_r[r];
        rs += __shfl_xor(rs, 1);
        rs += __shfl_xor(rs, 2);
        rs += __shfl_xor(rs, 4);
        rs += __shfl_xor(rs, 8);
        float rinv = 1.0f / rs;
#pragma unroll
        for (int ht = 0; ht < 4; ++ht) {
            size_t idx = (bT + q0 + w * 16 + lg * 4 + r) * DM + h * 64 + ht * 16 + lx;
            float v = acc[ht][r] * rinv;
            u16 hh = f2b(v);
            aoh[idx] = hh;
            aol[idx] = f2b(v - b2f(hh));
        }
    }
}

// ---------------- gate (fp32, unchanged) ----------------
__global__ __launch_bounds__(64) void gate_k(const float* __restrict__ h2,
                                             const float* __restrict__ gw,
                                             const float* __restrict__ gb,
                                             int* __restrict__ top2i,
                                             float* __restrict__ top2w,
                                             int* __restrict__ counts) {
    int n = blockIdx.x;
    int lane = threadIdx.x;
    float acc[8] = {};
    for (int d = lane; d < DM; d += 64) {
        float hv = h2[(size_t)n * DM + d];
        const float4 g0 = ((const float4*)&gw[d * 8])[0];
        const float4 g1 = ((const float4*)&gw[d * 8])[1];
        acc[0] = fmaf(hv, g0.x, acc[0]); acc[1] = fmaf(hv, g0.y, acc[1]);
        acc[2] = fmaf(hv, g0.z, acc[2]); acc[3] = fmaf(hv, g0.w, acc[3]);
        acc[4] = fmaf(hv, g1.x, acc[4]); acc[5] = fmaf(hv, g1.y, acc[5]);
        acc[6] = fmaf(hv, g1.z, acc[6]); acc[7] = fmaf(hv, g1.w, acc[7]);
    }
#pragma unroll
    for (int e = 0; e < 8; ++e)
        for (int off = 32; off; off >>= 1) acc[e] += __shfl_down(acc[e], off);
    if (lane == 0) {
        float s[8];
#pragma unroll
        for (int e = 0; e < 8; ++e) s[e] = 1.0f / (1.0f + expf(-acc[e])) + gb[e];
        int i0 = 0;
#pragma unroll
        for (int e = 1; e < 8; ++e) if (s[e] > s[i0]) i0 = e;
        int i1 = (i0 == 0) ? 1 : 0;
#pragma unroll
        for (int e = 0; e < 8; ++e) if (e != i0 && s[e] > s[i1]) i1 = e;
        float w0 = s[i0], w1 = s[i1];
        float norm = 1.0f / (w0 + w1 + 1e-20f);
        top2i[n * 2] = i0; top2i[n * 2 + 1] = i1;
        top2w[n * 2] = w0 * norm; top2w[n * 2 + 1] = w1 * norm;
        atomicAdd(&counts[i0], 1);
        atomicAdd(&counts[i1], 1);
    }
}

__global__ void zero16_k(int* p) { if (threadIdx.x < 16) p[threadIdx.x] = 0; }

__global__ void scan_k(const int* __restrict__ counts, int* __restrict__ segs) {
    if (threadIdx.x == 0) {
        segs[0] = 0;
        for (int e = 0; e < NE; ++e) segs[e + 1] = segs[e] + counts[e];
    }
}

__global__ void scatter_k(const int* __restrict__ top2i, const float* __restrict__ top2w,
                          const int* __restrict__ segs, int* __restrict__ cursor,
                          int* __restrict__ list, float* __restrict__ wslot,
                          int* __restrict__ slot_of) {
    int idx = blockIdx.x * blockDim.x + threadIdx.x;
    if (idx >= NTOK * 2) return;
    int e = top2i[idx];
    int pos = segs[e] + atomicAdd(&cursor[e], 1);
    list[pos] = idx >> 1;
    wslot[pos] = top2w[idx];
    slot_of[idx] = pos;
}

// ---------------- bf16 MFMA GEMM (MoE path) with global_load_lds staging ----------------
template <int EPI, int MOE, int GATHER>
__global__ __launch_bounds__(256) void mgemm_k(const u16* __restrict__ A,
                                               const u16* __restrict__ Bt,
                                               const float* __restrict__ R,
                                               const float* __restrict__ wslot,
                                               const int* __restrict__ list,
                                               const int* __restrict__ segs,
                                               float* __restrict__ Cf,
                                               u16* __restrict__ Cb,
                                               int M, int N, int K) {
    __shared__ u16 As[128 * 32];
    __shared__ u16 Bs[128 * 32];
    int e = MOE ? blockIdx.z : 0;
    int base = 0, cnt = M;
    if (MOE) { base = segs[e]; cnt = segs[e + 1] - base; }
    int m0 = blockIdx.y * 128;
    if (m0 >= cnt) return;
    int n0 = blockIdx.x * 128;
    const u16* Bte = Bt + (size_t)e * N * K;
    int t = threadIdx.x;
    int l = t & 63, w = t >> 6;
    int wr = w >> 1, wc = w & 1;
    int lx = l & 15, lg = l >> 4;
    int srow = t >> 2;
    int cs = (t & 3) ^ ((srow & 3) ^ ((t >> 4) & 3));
    const u16* ag[2];
    const u16* bg[2];
#pragma unroll
    for (int i = 0; i < 2; ++i) {
        int r = m0 + i * 64 + srow;
        int ar;
        if (MOE) {
            int rc = r < cnt ? r : cnt - 1;
            ar = GATHER ? list[base + rc] : base + rc;
        } else {
            ar = r;
        }
        ag[i] = A + (size_t)ar * K + cs * 8;
        bg[i] = Bte + (size_t)(n0 + i * 64 + srow) * K + cs * 8;
    }
    f4v acc[4][4];
#pragma unroll
    for (int m = 0; m < 4; ++m)
#pragma unroll
        for (int n = 0; n < 4; ++n) acc[m][n] = (f4v)0.0f;
    int keyr = (lx & 3) ^ ((lx >> 2) & 3);
    int chb = (lg ^ keyr) << 4;
    int aoff[4], boff[4];
#pragma unroll
    for (int m = 0; m < 4; ++m) aoff[m] = ((wr * 64 + m * 16 + lx) << 6) + chb;
#pragma unroll
    for (int n = 0; n < 4; ++n) boff[n] = ((wc * 64 + n * 16 + lx) << 6) + chb;
    int wb = w * 1024;
    for (int k0 = 0; k0 < K; k0 += 32) {
        __syncthreads();
        gload16(ag[0] + k0, (char*)As + wb);
        gload16(ag[1] + k0, (char*)As + wb + 4096);
        gload16(bg[0] + k0, (char*)Bs + wb);
        gload16(bg[1] + k0, (char*)Bs + wb + 4096);
        __syncthreads();
        b8v af[4], bf[4];
#pragma unroll
        for (int m = 0; m < 4; ++m) af[m] = *(const b8v*)((const char*)As + aoff[m]);
#pragma unroll
        for (int n = 0; n < 4; ++n) bf[n] = *(const b8v*)((const char*)Bs + boff[n]);
#pragma unroll
        for (int m = 0; m < 4; ++m)
#pragma unroll
            for (int n = 0; n < 4; ++n)
                acc[m][n] = __builtin_amdgcn_mfma_f32_16x16x32_bf16(af[m], bf[n], acc[m][n], 0, 0, 0);
    }
#pragma unroll
    for (int m = 0; m < 4; ++m) {
        int r0l = m0 + wr * 64 + m * 16 + ((l >> 4) << 2);
#pragma unroll
        for (int n = 0; n < 4; ++n) {
            int col = n0 + wc * 64 + n * 16 + (l & 15);
            f4v c = acc[m][n];
#pragma unroll
            for (int j = 0; j < 4; ++j) {
                int row = r0l + j;
                if (MOE && row >= cnt) continue;
                float v = c[j];
                if (EPI == 1) {
                    v = silu_f(v);
                    Cb[(size_t)(base + row) * N + col] = f2b(v);
                } else if (EPI == 2) {
                    size_t idx = (size_t)row * N + col;
                    Cf[idx] = v + R[idx];
                } else if (EPI == 3) {
                    Cf[(size_t)(base + row) * N + col] = v * wslot[base + row];
                } else {
                    Cf[(size_t)row * N + col] = v;
                }
            }
        }
    }
}

// ---------------- combine ----------------
__global__ __launch_bounds__(256) void combine_k(const float* __restrict__ eout,
                                                 const int* __restrict__ slot_of,
                                                 float* __restrict__ out) {
    int idx = blockIdx.x * blockDim.x + threadIdx.x;
    int n = idx >> 8;
    int c = idx & 255;
    const float4 a = ((const float4*)(eout + (size_t)slot_of[n * 2] * DM))[c];
    const float4 b = ((const float4*)(eout + (size_t)slot_of[n * 2 + 1] * DM))[c];
    float4 o = ((float4*)out)[idx];
    o.x += a.x + b.x; o.y += a.y + b.y; o.z += a.z + b.z; o.w += a.w + b.w;
    ((float4*)out)[idx] = o;
}

extern "C" void kernel_launch(void* const* d_in, const int* in_sizes, int n_in,
                              void* d_out, int out_size, void* d_ws, size_t ws_size,
                              hipStream_t stream) {
    (void)in_sizes; (void)n_in; (void)out_size; (void)ws_size;
    const float* x   = (const float*)d_in[0];
    const float* anw = (const float*)d_in[1];
    const float* wq  = (const float*)d_in[2];
    const float* wk  = (const float*)d_in[3];
    const float* wv  = (const float*)d_in[4];
    const float* wo  = (const float*)d_in[5];
    const float* fnw = (const float*)d_in[6];
    const float* gw  = (const float*)d_in[7];
    const float* gb  = (const float*)d_in[8];
    const float* ew1 = (const float*)d_in[9];
    const float* ew2 = (const float*)d_in[10];
    const float* sw1 = (const float*)d_in[11];
    const float* sw2 = (const float*)d_in[12];
    float* out = (float*)d_out;

#define WSOFF(mb) ((char*)d_ws + (size_t)(mb) * 1048576)
    // weights (persistent): 0..82 MB
    u16* qkvT_h = (u16*)WSOFF(0);    // 1536x1024
    u16* qkvT_l = (u16*)WSOFF(3);
    u16* woT_h  = (u16*)WSOFF(6);    // 1024x1024
    u16* woT_l  = (u16*)WSOFF(8);
    u16* sw1t   = (u16*)WSOFF(10);   // 2048x1024
    u16* sw2t   = (u16*)WSOFF(14);   // 1024x2048
    u16* ew1t   = (u16*)WSOFF(18);   // 8 x 2048x1024
    u16* ew2t   = (u16*)WSOFF(50);   // 8 x 1024x2048
    // activations (lifetime-overlapped):
    float* qkv  = (float*)WSOFF(82);   // 4096x1536 f32; dead after rope_split/vtrans
    float* h2f  = (float*)WSOFF(82);   // h2 f32 (after qkv dead)
    u16* h_hi   = (u16*)WSOFF(106);    // h split; dead after QKV gemm
    u16* h_lo   = (u16*)WSOFF(114);
    u16* ao_hi  = (u16*)WSOFF(106);    // ao split (written by mattn); dead after Wo gemm
    u16* ao_lo  = (u16*)WSOFF(114);
    u16* q_hi   = (u16*)WSOFF(122);    // q split; dead after attn
    u16* q_lo   = (u16*)WSOFF(130);
    u16* k_hi   = (u16*)WSOFF(138);    // k split
    u16* k_lo   = (u16*)WSOFF(140);
    u16* vT_hi  = (u16*)WSOFF(142);    // vT split
    u16* vT_lo  = (u16*)WSOFF(144);
    float* x1   = (float*)WSOFF(146);  // x1 f32
    u16* h2b    = (u16*)WSOFF(162);    // h2 bf16
    u16* midb   = (u16*)WSOFF(170);    // shared mid bf16
    u16* hmidb  = (u16*)WSOFF(122);    // routed mid bf16 (after attn/Wo dead)
    float* eoutb = (float*)WSOFF(154); // expert out f32
    int* meta0  = (int*)WSOFF(186);
    int*   top2i  = meta0;
    float* top2w  = (float*)(meta0 + 8192);
    int*   counts = meta0 + 16384;
    int*   cursor = meta0 + 16392;
    int*   segs   = meta0 + 16400;
    int*   list   = meta0 + 16416;
    float* wslot  = (float*)(meta0 + 16416 + 8192);
    int*   slot_of = meta0 + 16416 + 16384;
    float* ropetab = (float*)WSOFF(190);  // 2048 x 32 x 2 f32

    // ---- weight prep + rope table ----
    ropetab_k<<<256, 256, 0, stream>>>(ropetab);
    tcast2_k<<<dim3(32, 32), 256, 0, stream>>>(wq, qkvT_h, qkvT_l, DM, 1024);
    tcast2_k<<<dim3(8, 32), 256, 0, stream>>>(wk, qkvT_h + 1024 * 1024, qkvT_l + 1024 * 1024, DM, 256);
    tcast2_k<<<dim3(8, 32), 256, 0, stream>>>(wv, qkvT_h + 1280 * 1024, qkvT_l + 1280 * 1024, DM, 256);
    tcast2_k<<<dim3(32, 32), 256, 0, stream>>>(wo, woT_h, woT_l, DM, DM);
    tcast_k<<<dim3(NFF / 32, DM / 32, 1), 256, 0, stream>>>(sw1, sw1t, DM, NFF);
    tcast_k<<<dim3(DM / 32, NFF / 32, 1), 256, 0, stream>>>(sw2, sw2t, NFF, DM);
    tcast_k<<<dim3(NFF / 32, DM / 32, NE), 256, 0, stream>>>(ew1, ew1t, DM, NFF);
    tcast_k<<<dim3(DM / 32, NFF / 32, NE), 256, 0, stream>>>(ew2, ew2t, NFF, DM);

    // 1. h = rmsnorm(x) -> hi/lo split
    rmsnorm2_k<0><<<NTOK, 256, 0, stream>>>(x, anw, h_hi, h_lo, nullptr);
    // 2. fused QKV projection (split MFMA) -> qkv f32
    sgemm_k<0><<<dim3(QKVN / 128, NTOK / 128), 256, 0, stream>>>(
        h_hi, h_lo, qkvT_h, qkvT_l, nullptr, qkv, NTOK, QKVN, DM);
    // 3. fused RoPE + split for q,k; V transpose+split
    rope_split_k<<<2048, 256, 0, stream>>>(qkv, ropetab, 0, 1024, q_hi, q_lo);
    rope_split_k<<<512, 256, 0, stream>>>(qkv, ropetab, 1024, 256, k_hi, k_lo);
    vtrans_k<<<dim3(8, 128), 256, 0, stream>>>(qkv, vT_hi, vT_lo);
    // 4. attention -> ao hi/lo split (direct)
    mattn_k<<<dim3(32, 32), 256, 0, stream>>>(q_hi, q_lo, k_hi, k_lo, vT_hi, vT_lo, ao_hi, ao_lo);
    // 5. x1 = ao @ wo + x
    sgemm_k<2><<<dim3(DM / 128, NTOK / 128), 256, 0, stream>>>(
        ao_hi, ao_lo, woT_h, woT_l, x, x1, NTOK, DM, DM);
    // 6. h2 = rmsnorm(x1) -> f32 (gate) + bf16 (MoE)
    rmsnorm2_k<1><<<NTOK, 256, 0, stream>>>(x1, fnw, h2b, nullptr, h2f);
    // 7. gate + routing
    zero16_k<<<1, 64, 0, stream>>>(counts);
    gate_k<<<NTOK, 64, 0, stream>>>(h2f, gw, gb, top2i, top2w, counts);
    scan_k<<<1, 1, 0, stream>>>(counts, segs);
    scatter_k<<<32, 256, 0, stream>>>(top2i, top2w, segs, cursor, list, wslot, slot_of);
    // 8. shared expert
    mgemm_k<1, 0, 0><<<dim3(NFF / 128, NTOK / 128, 1), 256, 0, stream>>>(
        h2b, sw1t, nullptr, nullptr, nullptr, nullptr, nullptr, midb, NTOK, NFF, DM);
    mgemm_k<2, 0, 0><<<dim3(DM / 128, NTOK / 128, 1), 256, 0, stream>>>(
        midb, sw2t, x1, nullptr, nullptr, nullptr, out, nullptr, NTOK, DM, NFF);
    // 9. routed experts
    mgemm_k<1, 1, 1><<<dim3(NFF / 128, NTOK / 128, NE), 256, 0, stream>>>(
        h2b, ew1t, nullptr, nullptr, list, segs, nullptr, hmidb, NTOK, NFF, DM);
    mgemm_k<3, 1, 0><<<dim3(DM / 128, NTOK / 128, NE), 256, 0, stream>>>(
        hmidb, ew2t, nullptr, wslot, nullptr, segs, eoutb, nullptr, 2 * NTOK, DM, NFF);
    combine_k<<<NTOK, 256, 0, stream>>>(eoutb, slot_of, out);
#undef WSOFF
}

// Round 7
// 1032.643 us; speedup vs baseline: 1.1907x; 1.1907x over previous
//
#include <hip/hip_runtime.h>
#include <math.h>

#define NTOK 4096
#define DM 1024
#define TSEQ 2048
#define NH 16
#define NKV 4
#define HDIM 64
#define NE 8
#define NFF 2048
#define QKVN 1536

typedef float f4v __attribute__((ext_vector_type(4)));
typedef short b8v __attribute__((ext_vector_type(8)));
typedef unsigned short u16;

__device__ __forceinline__ float silu_f(float v) { return v / (1.0f + expf(-v)); }

__device__ __forceinline__ u16 f2b(float f) {  // RNE
    union { float f; unsigned u; } x{f};
    unsigned r = (x.u + 0x7FFFu + ((x.u >> 16) & 1u)) >> 16;
    return (u16)r;
}
__device__ __forceinline__ u16 f2bt(float f) {  // truncate
    union { float f; unsigned u; } x{f};
    return (u16)(x.u >> 16);
}
__device__ __forceinline__ float b2f(u16 b) {
    union { unsigned u; float f; } x;
    x.u = ((unsigned)b) << 16;
    return x.f;
}

// async global->LDS, 16B per lane; LDS dest = wave-uniform base + lane*16
__device__ __forceinline__ void gload16(const void* g, void* l) {
    typedef __attribute__((address_space(1))) const void gv;
    typedef __attribute__((address_space(3))) void lv;
    __builtin_amdgcn_global_load_lds((gv*)g, (lv*)l, 16, 0, 0);
}

// ---------------- RMSNorm, MODE 0: hi/lo split; MODE 1: f32 + plain bf16 ----
template <int MODE>
__global__ __launch_bounds__(256) void rmsnorm2_k(const float* __restrict__ x,
                                                  const float* __restrict__ w,
                                                  u16* __restrict__ oh, u16* __restrict__ ol,
                                                  float* __restrict__ of) {
    int row = blockIdx.x;
    int tid = threadIdx.x;
    const float4 v = ((const float4*)(x + (size_t)row * DM))[tid];
    float ss = v.x * v.x + v.y * v.y + v.z * v.z + v.w * v.w;
    for (int off = 32; off; off >>= 1) ss += __shfl_down(ss, off);
    __shared__ float red[4];
    if ((tid & 63) == 0) red[tid >> 6] = ss;
    __syncthreads();
    float tot = red[0] + red[1] + red[2] + red[3];
    float inv = rsqrtf(tot * (1.0f / DM) + 1e-6f);
    const float4 wv = ((const float4*)w)[tid];
    float o[4];
    o[0] = v.x * inv * wv.x; o[1] = v.y * inv * wv.y;
    o[2] = v.z * inv * wv.z; o[3] = v.w * inv * wv.w;
    if (MODE == 1) {
        float4 f; f.x = o[0]; f.y = o[1]; f.z = o[2]; f.w = o[3];
        ((float4*)(of + (size_t)row * DM))[tid] = f;
        ushort4 hb;
        hb.x = f2b(o[0]); hb.y = f2b(o[1]); hb.z = f2b(o[2]); hb.w = f2b(o[3]);
        ((ushort4*)(oh + (size_t)row * DM))[tid] = hb;
    } else {
        ushort4 hb, lb;
#pragma unroll
        for (int i = 0; i < 4; ++i) {
            u16 h = f2b(o[i]);
            u16 l = f2b(o[i] - b2f(h));
            ((u16*)&hb)[i] = h;
            ((u16*)&lb)[i] = l;
        }
        ((ushort4*)(oh + (size_t)row * DM))[tid] = hb;
        ((ushort4*)(ol + (size_t)row * DM))[tid] = lb;
    }
}

// ---------------- RoPE cos/sin table ----------------
__global__ __launch_bounds__(256) void ropetab_k(float* __restrict__ tab) {
    int idx = blockIdx.x * 256 + threadIdx.x;
    if (idx >= TSEQ * 32) return;
    int t = idx >> 5, j = idx & 31;
    float inv = expf(-(float)j * (0.03125f * logf(10000.0f)));
    float s, c;
    sincosf((float)t * inv, &s, &c);
    tab[t * 64 + j * 2] = c;
    tab[t * 64 + j * 2 + 1] = s;
}

// ---------------- fused RoPE + hi/lo split ----------------
__global__ __launch_bounds__(256) void rope_split_k(const float* __restrict__ qkv,
                                                    const float* __restrict__ tab,
                                                    int colbase, int cols,
                                                    u16* __restrict__ oh, u16* __restrict__ ol) {
    int idx = blockIdx.x * 256 + threadIdx.x;
    int cpr = cols >> 3;
    int row = idx / cpr;
    int cc = (idx - row * cpr) << 3;
    const float* p = qkv + (size_t)row * QKVN + colbase + cc;
    const float4 a = *(const float4*)p;
    const float4 b = *(const float4*)(p + 4);
    float vv[8] = {a.x, a.y, a.z, a.w, b.x, b.y, b.z, b.w};
    int tpos = row & (TSEQ - 1);
    const float* tb = tab + tpos * 64 + ((cc & 63) >> 1) * 2;
    float ov[8];
#pragma unroll
    for (int q = 0; q < 4; ++q) {
        float c = tb[q * 2], s = tb[q * 2 + 1];
        float x0 = vv[2 * q], x1 = vv[2 * q + 1];
        ov[2 * q] = x0 * c - x1 * s;
        ov[2 * q + 1] = x0 * s + x1 * c;
    }
    ushort4 h0, h1, l0, l1;
#pragma unroll
    for (int i = 0; i < 8; ++i) {
        u16 h = f2b(ov[i]);
        u16 l = f2b(ov[i] - b2f(h));
        if (i < 4) { ((u16*)&h0)[i] = h; ((u16*)&l0)[i] = l; }
        else       { ((u16*)&h1)[i - 4] = h; ((u16*)&l1)[i - 4] = l; }
    }
    u16* po = oh + (size_t)row * cols + cc;
    u16* pl = ol + (size_t)row * cols + cc;
    *(ushort4*)po = h0; *(ushort4*)(po + 4) = h1;
    *(ushort4*)pl = l0; *(ushort4*)(pl + 4) = l1;
}

// ---------------- V transpose + split ----------------
__global__ __launch_bounds__(256) void vtrans_k(const float* __restrict__ qkv,
                                                u16* __restrict__ oh, u16* __restrict__ ol) {
    __shared__ float tl[32][33];
    int c0 = blockIdx.x << 5;
    int r0 = blockIdx.y << 5;
    int lr = threadIdx.x >> 3, lc = (threadIdx.x & 7) << 2;
    const float4 v = *(const float4*)&qkv[(size_t)(r0 + lr) * QKVN + 1280 + c0 + lc];
    tl[lr][lc] = v.x; tl[lr][lc + 1] = v.y; tl[lr][lc + 2] = v.z; tl[lr][lc + 3] = v.w;
    __syncthreads();
    int b = r0 >> 11;
    size_t obase = ((size_t)(b * 256 + c0 + lr)) * TSEQ + (r0 & 2047) + lc;
    ushort4 h4, l4;
#pragma unroll
    for (int i = 0; i < 4; ++i) {
        float f = tl[lc + i][lr];
        u16 h = f2b(f);
        u16 l = f2b(f - b2f(h));
        ((u16*)&h4)[i] = h; ((u16*)&l4)[i] = l;
    }
    *(ushort4*)&oh[obase] = h4;
    *(ushort4*)&ol[obase] = l4;
}

// ---------------- weight transpose + split cast ----------------
__global__ __launch_bounds__(256) void tcast2_k(const float* __restrict__ in,
                                                u16* __restrict__ oh, u16* __restrict__ ol,
                                                int R, int C) {
    __shared__ float tl[32][33];
    int r0 = blockIdx.y << 5, c0 = blockIdx.x << 5;
    int lr = threadIdx.x >> 3, lc = (threadIdx.x & 7) << 2;
    const float4 v = *(const float4*)&in[(size_t)(r0 + lr) * C + c0 + lc];
    tl[lr][lc] = v.x; tl[lr][lc + 1] = v.y; tl[lr][lc + 2] = v.z; tl[lr][lc + 3] = v.w;
    __syncthreads();
    ushort4 h4, l4;
#pragma unroll
    for (int i = 0; i < 4; ++i) {
        float f = tl[lc + i][lr];
        u16 h = f2b(f);
        u16 l = f2b(f - b2f(h));
        ((u16*)&h4)[i] = h; ((u16*)&l4)[i] = l;
    }
    size_t ob = (size_t)(c0 + lr) * R + r0 + lc;
    *(ushort4*)&oh[ob] = h4;
    *(ushort4*)&ol[ob] = l4;
}

// ---------------- plain weight transpose + bf16 cast (MoE weights) ----------------
__global__ __launch_bounds__(256) void tcast_k(const float* __restrict__ in,
                                               u16* __restrict__ out, int R, int C) {
    size_t boff = (size_t)blockIdx.z * R * C;
    in += boff; out += boff;
    __shared__ float tl[32][33];
    int r0 = blockIdx.y << 5, c0 = blockIdx.x << 5;
    int lr = threadIdx.x >> 3, lc = (threadIdx.x & 7) << 2;
    const float4 v = *(const float4*)&in[(size_t)(r0 + lr) * C + c0 + lc];
    tl[lr][lc] = v.x; tl[lr][lc + 1] = v.y; tl[lr][lc + 2] = v.z; tl[lr][lc + 3] = v.w;
    __syncthreads();
    ushort4 o;
    o.x = f2b(tl[lc + 0][lr]); o.y = f2b(tl[lc + 1][lr]);
    o.z = f2b(tl[lc + 2][lr]); o.w = f2b(tl[lc + 3][lr]);
    *(ushort4*)&out[(size_t)(c0 + lr) * R + r0 + lc] = o;
}

// ---------------- split-bf16 MFMA GEMM with global_load_lds staging ----------------
template <int EPI>  // 0 plain f32, 2 + residual R
__global__ __launch_bounds__(256) void sgemm_k(const u16* __restrict__ Ah,
                                               const u16* __restrict__ Al,
                                               const u16* __restrict__ Bh,
                                               const u16* __restrict__ Bl,
                                               const float* __restrict__ Rr,
                                               float* __restrict__ C,
                                               int M, int N, int K) {
    __shared__ u16 Ash[128 * 32], Asl[128 * 32], Bsh[128 * 32], Bsl[128 * 32];
    int t = threadIdx.x;
    int l = t & 63, w = t >> 6;
    int wr = w >> 1, wc = w & 1;
    int lx = l & 15, lg = l >> 4;
    int n0 = blockIdx.x * 128, m0 = blockIdx.y * 128;
    int srow = t >> 2;
    int cs = (t & 3) ^ ((srow & 3) ^ ((t >> 4) & 3));
    const u16 *agh[2], *agl[2], *bgh[2], *bgl[2];
#pragma unroll
    for (int i = 0; i < 2; ++i) {
        size_t ao = (size_t)(m0 + i * 64 + srow) * K + cs * 8;
        size_t bo = (size_t)(n0 + i * 64 + srow) * K + cs * 8;
        agh[i] = Ah + ao; agl[i] = Al + ao;
        bgh[i] = Bh + bo; bgl[i] = Bl + bo;
    }
    f4v acc[4][4];
#pragma unroll
    for (int m = 0; m < 4; ++m)
#pragma unroll
        for (int n = 0; n < 4; ++n) acc[m][n] = (f4v)0.0f;
    int keyr = (lx & 3) ^ ((lx >> 2) & 3);
    int chb = (lg ^ keyr) << 4;
    int aoff[4], boff[4];
#pragma unroll
    for (int m = 0; m < 4; ++m) aoff[m] = ((wr * 64 + m * 16 + lx) << 6) + chb;
#pragma unroll
    for (int n = 0; n < 4; ++n) boff[n] = ((wc * 64 + n * 16 + lx) << 6) + chb;
    int wb = w * 1024;
    for (int k0 = 0; k0 < K; k0 += 32) {
        __syncthreads();
        gload16(agh[0] + k0, (char*)Ash + wb);
        gload16(agh[1] + k0, (char*)Ash + wb + 4096);
        gload16(agl[0] + k0, (char*)Asl + wb);
        gload16(agl[1] + k0, (char*)Asl + wb + 4096);
        gload16(bgh[0] + k0, (char*)Bsh + wb);
        gload16(bgh[1] + k0, (char*)Bsh + wb + 4096);
        gload16(bgl[0] + k0, (char*)Bsl + wb);
        gload16(bgl[1] + k0, (char*)Bsl + wb + 4096);
        __syncthreads();
        b8v afh[4], afl[4], bfh[4], bfl[4];
#pragma unroll
        for (int m = 0; m < 4; ++m) {
            afh[m] = *(const b8v*)((const char*)Ash + aoff[m]);
            afl[m] = *(const b8v*)((const char*)Asl + aoff[m]);
        }
#pragma unroll
        for (int n = 0; n < 4; ++n) {
            bfh[n] = *(const b8v*)((const char*)Bsh + boff[n]);
            bfl[n] = *(const b8v*)((const char*)Bsl + boff[n]);
        }
#pragma unroll
        for (int m = 0; m < 4; ++m)
#pragma unroll
            for (int n = 0; n < 4; ++n) {
                acc[m][n] = __builtin_amdgcn_mfma_f32_16x16x32_bf16(afl[m], bfh[n], acc[m][n], 0, 0, 0);
                acc[m][n] = __builtin_amdgcn_mfma_f32_16x16x32_bf16(afh[m], bfl[n], acc[m][n], 0, 0, 0);
                acc[m][n] = __builtin_amdgcn_mfma_f32_16x16x32_bf16(afh[m], bfh[n], acc[m][n], 0, 0, 0);
            }
    }
#pragma unroll
    for (int m = 0; m < 4; ++m) {
        int r0l = m0 + wr * 64 + m * 16 + ((l >> 4) << 2);
#pragma unroll
        for (int n = 0; n < 4; ++n) {
            int col = n0 + wc * 64 + n * 16 + (l & 15);
            f4v c = acc[m][n];
#pragma unroll
            for (int j = 0; j < 4; ++j) {
                size_t idx = (size_t)(r0l + j) * N + col;
                float v = c[j];
                if (EPI == 2) v += Rr[idx];
                C[idx] = v;
            }
        }
    }
}

// ---------------- split-bf16 MFMA flash attention v4: paired q-tiles + KV-split ----
// grid (16, 32, 2): block = q-tiles {bx, 31-bx} (uniform), z = kv half.
// m==0 softmax makes halves additive: write unnormalized acc + partial l.
__global__ __launch_bounds__(256) void mattn_k(const u16* __restrict__ qh, const u16* __restrict__ ql,
                                               const u16* __restrict__ kh, const u16* __restrict__ kl,
                                               const u16* __restrict__ vth, const u16* __restrict__ vtl,
                                               float* __restrict__ pacc, float* __restrict__ pl) {
    __shared__ short plds[4][2][16][72];
    int t = threadIdx.x, l = t & 63, w = t >> 6;
    int bh = blockIdx.y, b = bh >> 4, h = bh & 15, kvh = h >> 2;
    int z = blockIdx.z;
    size_t zoff = (size_t)z * NTOK * DM;
    int zloff = z * NTOK * 16;
    size_t bT = (size_t)b * TSEQ;
    int lx = l & 15, lg = l >> 4;
#pragma unroll
    for (int half = 0; half < 2; ++half) {
        int qt = half ? (31 - blockIdx.x) : blockIdx.x;
        int q0 = qt * 64;
        int ntile = qt + 1;
        int klo = (ntile * z) >> 1;
        int khi = (ntile * (z + 1)) >> 1;
        b8v qfh[2], qfl[2];
        {
            size_t qo = (bT + q0 + w * 16 + lx) * DM + h * 64 + lg * 8;
            qfh[0] = *(const b8v*)(qh + qo);
            qfh[1] = *(const b8v*)(qh + qo + 32);
            qfl[0] = *(const b8v*)(ql + qo);
            qfl[1] = *(const b8v*)(ql + qo + 32);
        }
        f4v acc[4];
#pragma unroll
        for (int ht = 0; ht < 4; ++ht) acc[ht] = (f4v)0.0f;
        float l_r[4] = {0.0f, 0.0f, 0.0f, 0.0f};
        int qg[4];
#pragma unroll
        for (int r = 0; r < 4; ++r) qg[r] = q0 + w * 16 + lg * 4 + r;
        for (int kt = klo; kt < khi; ++kt) {
            int kv0 = kt << 6;
            f4v s[4];
#pragma unroll
            for (int st = 0; st < 4; ++st) {
                size_t ko = (bT + kv0 + st * 16 + lx) * 256 + kvh * 64 + lg * 8;
                b8v kf0h = *(const b8v*)(kh + ko);
                b8v kf1h = *(const b8v*)(kh + ko + 32);
                b8v kf0l = *(const b8v*)(kl + ko);
                b8v kf1l = *(const b8v*)(kl + ko + 32);
                f4v ss = (f4v)0.0f;
                ss = __builtin_amdgcn_mfma_f32_16x16x32_bf16(qfl[0], kf0h, ss, 0, 0, 0);
                ss = __builtin_amdgcn_mfma_f32_16x16x32_bf16(qfh[0], kf0l, ss, 0, 0, 0);
                ss = __builtin_amdgcn_mfma_f32_16x16x32_bf16(qfh[0], kf0h, ss, 0, 0, 0);
                ss = __builtin_amdgcn_mfma_f32_16x16x32_bf16(qfl[1], kf1h, ss, 0, 0, 0);
                ss = __builtin_amdgcn_mfma_f32_16x16x32_bf16(qfh[1], kf1l, ss, 0, 0, 0);
                ss = __builtin_amdgcn_mfma_f32_16x16x32_bf16(qfh[1], kf1h, ss, 0, 0, 0);
                s[st] = ss;
            }
            b8v vh0[4], vh1[4], vl0[4], vl1[4];
#pragma unroll
            for (int ht = 0; ht < 4; ++ht) {
                size_t vo = ((size_t)(b * 4 + kvh) * 64 + ht * 16 + lx) * TSEQ + kv0 + lg * 8;
                vh0[ht] = *(const b8v*)(vth + vo);
                vh1[ht] = *(const b8v*)(vth + vo + 32);
                vl0[ht] = *(const b8v*)(vtl + vo);
                vl1[ht] = *(const b8v*)(vtl + vo + 32);
            }
#pragma unroll
            for (int st = 0; st < 4; ++st)
#pragma unroll
                for (int r = 0; r < 4; ++r) {
                    float v = s[st][r] * 0.125f;
                    float p = (kv0 + st * 16 + lx > qg[r]) ? 0.0f : __expf(fminf(v, 60.0f));
                    l_r[r] += p;
                    u16 ph = f2bt(p);
                    u16 pv = f2bt(p - b2f(ph));
                    plds[w][0][lg * 4 + r][st * 16 + lx] = (short)ph;
                    plds[w][1][lg * 4 + r][st * 16 + lx] = (short)pv;
                }
            __threadfence_block();
            __builtin_amdgcn_sched_barrier(0);
            b8v pf0h = *(const b8v*)&plds[w][0][lx][lg * 8];
            b8v pf1h = *(const b8v*)&plds[w][0][lx][32 + lg * 8];
            b8v pf0l = *(const b8v*)&plds[w][1][lx][lg * 8];
            b8v pf1l = *(const b8v*)&plds[w][1][lx][32 + lg * 8];
            __builtin_amdgcn_sched_barrier(0);
#pragma unroll
            for (int ht = 0; ht < 4; ++ht) {
                acc[ht] = __builtin_amdgcn_mfma_f32_16x16x32_bf16(pf0l, vh0[ht], acc[ht], 0, 0, 0);
                acc[ht] = __builtin_amdgcn_mfma_f32_16x16x32_bf16(pf0h, vl0[ht], acc[ht], 0, 0, 0);
                acc[ht] = __builtin_amdgcn_mfma_f32_16x16x32_bf16(pf0h, vh0[ht], acc[ht], 0, 0, 0);
                acc[ht] = __builtin_amdgcn_mfma_f32_16x16x32_bf16(pf1l, vh1[ht], acc[ht], 0, 0, 0);
                acc[ht] = __builtin_amdgcn_mfma_f32_16x16x32_bf16(pf1h, vl1[ht], acc[ht], 0, 0, 0);
                acc[ht] = __builtin_amdgcn_mfma_f32_16x16x32_bf16(pf1h, vh1[ht], acc[ht], 0, 0, 0);
            }
        }
        // epilogue: partial row-sum reduce + unnormalized acc writes
#pragma unroll
        for (int r = 0; r < 4; ++r) {
            float rs = l_r[r];
            rs += __shfl_xor(rs, 1);
            rs += __shfl_xor(rs, 2);
            rs += __shfl_xor(rs, 4);
            rs += __shfl_xor(rs, 8);
            size_t row = bT + q0 + w * 16 + lg * 4 + r;
            if (lx == 0) pl[zloff + row * 16 + h] = rs;
#pragma unroll
            for (int ht = 0; ht < 4; ++ht)
                pacc[zoff + row * DM + h * 64 + ht * 16 + lx] = acc[ht][r];
        }
    }
}

// ---------------- attention combine: (a0+a1)/(l0+l1) -> ao hi/lo split ----------------
__global__ __launch_bounds__(256) void atcomb_k(const float* __restrict__ pacc,
                                                const float* __restrict__ pl,
                                                u16* __restrict__ aoh, u16* __restrict__ aol) {
    int row = blockIdx.x;
    int tid = threadIdx.x;
    int c = tid << 2;
    int h = c >> 6;
    float l0 = pl[row * 16 + h];
    float l1 = pl[NTOK * 16 + row * 16 + h];
    float rinv = 1.0f / (l0 + l1);
    const float4 a0 = *(const float4*)&pacc[(size_t)row * DM + c];
    const float4 a1 = *(const float4*)&pacc[(size_t)NTOK * DM + (size_t)row * DM + c];
    float v[4] = {(a0.x + a1.x) * rinv, (a0.y + a1.y) * rinv,
                  (a0.z + a1.z) * rinv, (a0.w + a1.w) * rinv};
    ushort4 hb, lb;
#pragma unroll
    for (int i = 0; i < 4; ++i) {
        u16 hh = f2b(v[i]);
        ((u16*)&hb)[i] = hh;
        ((u16*)&lb)[i] = f2b(v[i] - b2f(hh));
    }
    *(ushort4*)&aoh[(size_t)row * DM + c] = hb;
    *(ushort4*)&aol[(size_t)row * DM + c] = lb;
}

// ---------------- gate (fp32, unchanged) ----------------
__global__ __launch_bounds__(64) void gate_k(const float* __restrict__ h2,
                                             const float* __restrict__ gw,
                                             const float* __restrict__ gb,
                                             int* __restrict__ top2i,
                                             float* __restrict__ top2w,
                                             int* __restrict__ counts) {
    int n = blockIdx.x;
    int lane = threadIdx.x;
    float acc[8] = {};
    for (int d = lane; d < DM; d += 64) {
        float hv = h2[(size_t)n * DM + d];
        const float4 g0 = ((const float4*)&gw[d * 8])[0];
        const float4 g1 = ((const float4*)&gw[d * 8])[1];
        acc[0] = fmaf(hv, g0.x, acc[0]); acc[1] = fmaf(hv, g0.y, acc[1]);
        acc[2] = fmaf(hv, g0.z, acc[2]); acc[3] = fmaf(hv, g0.w, acc[3]);
        acc[4] = fmaf(hv, g1.x, acc[4]); acc[5] = fmaf(hv, g1.y, acc[5]);
        acc[6] = fmaf(hv, g1.z, acc[6]); acc[7] = fmaf(hv, g1.w, acc[7]);
    }
#pragma unroll
    for (int e = 0; e < 8; ++e)
        for (int off = 32; off; off >>= 1) acc[e] += __shfl_down(acc[e], off);
    if (lane == 0) {
        float s[8];
#pragma unroll
        for (int e = 0; e < 8; ++e) s[e] = 1.0f / (1.0f + expf(-acc[e])) + gb[e];
        int i0 = 0;
#pragma unroll
        for (int e = 1; e < 8; ++e) if (s[e] > s[i0]) i0 = e;
        int i1 = (i0 == 0) ? 1 : 0;
#pragma unroll
        for (int e = 0; e < 8; ++e) if (e != i0 && s[e] > s[i1]) i1 = e;
        float w0 = s[i0], w1 = s[i1];
        float norm = 1.0f / (w0 + w1 + 1e-20f);
        top2i[n * 2] = i0; top2i[n * 2 + 1] = i1;
        top2w[n * 2] = w0 * norm; top2w[n * 2 + 1] = w1 * norm;
        atomicAdd(&counts[i0], 1);
        atomicAdd(&counts[i1], 1);
    }
}

__global__ void zero16_k(int* p) { if (threadIdx.x < 16) p[threadIdx.x] = 0; }

__global__ void scan_k(const int* __restrict__ counts, int* __restrict__ segs) {
    if (threadIdx.x == 0) {
        segs[0] = 0;
        for (int e = 0; e < NE; ++e) segs[e + 1] = segs[e] + counts[e];
    }
}

__global__ void scatter_k(const int* __restrict__ top2i, const float* __restrict__ top2w,
                          const int* __restrict__ segs, int* __restrict__ cursor,
                          int* __restrict__ list, float* __restrict__ wslot,
                          int* __restrict__ slot_of) {
    int idx = blockIdx.x * blockDim.x + threadIdx.x;
    if (idx >= NTOK * 2) return;
    int e = top2i[idx];
    int pos = segs[e] + atomicAdd(&cursor[e], 1);
    list[pos] = idx >> 1;
    wslot[pos] = top2w[idx];
    slot_of[idx] = pos;
}

// ---------------- bf16 MFMA GEMM (MoE path) with global_load_lds staging ----------------
template <int EPI, int MOE, int GATHER>
__global__ __launch_bounds__(256) void mgemm_k(const u16* __restrict__ A,
                                               const u16* __restrict__ Bt,
                                               const float* __restrict__ R,
                                               const float* __restrict__ wslot,
                                               const int* __restrict__ list,
                                               const int* __restrict__ segs,
                                               float* __restrict__ Cf,
                                               u16* __restrict__ Cb,
                                               int M, int N, int K) {
    __shared__ u16 As[128 * 32];
    __shared__ u16 Bs[128 * 32];
    int e = MOE ? blockIdx.z : 0;
    int base = 0, cnt = M;
    if (MOE) { base = segs[e]; cnt = segs[e + 1] - base; }
    int m0 = blockIdx.y * 128;
    if (m0 >= cnt) return;
    int n0 = blockIdx.x * 128;
    const u16* Bte = Bt + (size_t)e * N * K;
    int t = threadIdx.x;
    int l = t & 63, w = t >> 6;
    int wr = w >> 1, wc = w & 1;
    int lx = l & 15, lg = l >> 4;
    int srow = t >> 2;
    int cs = (t & 3) ^ ((srow & 3) ^ ((t >> 4) & 3));
    const u16* ag[2];
    const u16* bg[2];
#pragma unroll
    for (int i = 0; i < 2; ++i) {
        int r = m0 + i * 64 + srow;
        int ar;
        if (MOE) {
            int rc = r < cnt ? r : cnt - 1;
            ar = GATHER ? list[base + rc] : base + rc;
        } else {
            ar = r;
        }
        ag[i] = A + (size_t)ar * K + cs * 8;
        bg[i] = Bte + (size_t)(n0 + i * 64 + srow) * K + cs * 8;
    }
    f4v acc[4][4];
#pragma unroll
    for (int m = 0; m < 4; ++m)
#pragma unroll
        for (int n = 0; n < 4; ++n) acc[m][n] = (f4v)0.0f;
    int keyr = (lx & 3) ^ ((lx >> 2) & 3);
    int chb = (lg ^ keyr) << 4;
    int aoff[4], boff[4];
#pragma unroll
    for (int m = 0; m < 4; ++m) aoff[m] = ((wr * 64 + m * 16 + lx) << 6) + chb;
#pragma unroll
    for (int n = 0; n < 4; ++n) boff[n] = ((wc * 64 + n * 16 + lx) << 6) + chb;
    int wb = w * 1024;
    for (int k0 = 0; k0 < K; k0 += 32) {
        __syncthreads();
        gload16(ag[0] + k0, (char*)As + wb);
        gload16(ag[1] + k0, (char*)As + wb + 4096);
        gload16(bg[0] + k0, (char*)Bs + wb);
        gload16(bg[1] + k0, (char*)Bs + wb + 4096);
        __syncthreads();
        b8v af[4], bf[4];
#pragma unroll
        for (int m = 0; m < 4; ++m) af[m] = *(const b8v*)((const char*)As + aoff[m]);
#pragma unroll
        for (int n = 0; n < 4; ++n) bf[n] = *(const b8v*)((const char*)Bs + boff[n]);
#pragma unroll
        for (int m = 0; m < 4; ++m)
#pragma unroll
            for (int n = 0; n < 4; ++n)
                acc[m][n] = __builtin_amdgcn_mfma_f32_16x16x32_bf16(af[m], bf[n], acc[m][n], 0, 0, 0);
    }
#pragma unroll
    for (int m = 0; m < 4; ++m) {
        int r0l = m0 + wr * 64 + m * 16 + ((l >> 4) << 2);
#pragma unroll
        for (int n = 0; n < 4; ++n) {
            int col = n0 + wc * 64 + n * 16 + (l & 15);
            f4v c = acc[m][n];
#pragma unroll
            for (int j = 0; j < 4; ++j) {
                int row = r0l + j;
                if (MOE && row >= cnt) continue;
                float v = c[j];
                if (EPI == 1) {
                    v = silu_f(v);
                    Cb[(size_t)(base + row) * N + col] = f2b(v);
                } else if (EPI == 2) {
                    size_t idx = (size_t)row * N + col;
                    Cf[idx] = v + R[idx];
                } else if (EPI == 3) {
                    Cf[(size_t)(base + row) * N + col] = v * wslot[base + row];
                } else {
                    Cf[(size_t)row * N + col] = v;
                }
            }
        }
    }
}

// ---------------- combine ----------------
__global__ __launch_bounds__(256) void combine_k(const float* __restrict__ eout,
                                                 const int* __restrict__ slot_of,
                                                 float* __restrict__ out) {
    int idx = blockIdx.x * blockDim.x + threadIdx.x;
    int n = idx >> 8;
    int c = idx & 255;
    const float4 a = ((const float4*)(eout + (size_t)slot_of[n * 2] * DM))[c];
    const float4 b = ((const float4*)(eout + (size_t)slot_of[n * 2 + 1] * DM))[c];
    float4 o = ((float4*)out)[idx];
    o.x += a.x + b.x; o.y += a.y + b.y; o.z += a.z + b.z; o.w += a.w + b.w;
    ((float4*)out)[idx] = o;
}

extern "C" void kernel_launch(void* const* d_in, const int* in_sizes, int n_in,
                              void* d_out, int out_size, void* d_ws, size_t ws_size,
                              hipStream_t stream) {
    (void)in_sizes; (void)n_in; (void)out_size; (void)ws_size;
    const float* x   = (const float*)d_in[0];
    const float* anw = (const float*)d_in[1];
    const float* wq  = (const float*)d_in[2];
    const float* wk  = (const float*)d_in[3];
    const float* wv  = (const float*)d_in[4];
    const float* wo  = (const float*)d_in[5];
    const float* fnw = (const float*)d_in[6];
    const float* gw  = (const float*)d_in[7];
    const float* gb  = (const float*)d_in[8];
    const float* ew1 = (const float*)d_in[9];
    const float* ew2 = (const float*)d_in[10];
    const float* sw1 = (const float*)d_in[11];
    const float* sw2 = (const float*)d_in[12];
    float* out = (float*)d_out;

#define WSOFF(mb) ((char*)d_ws + (size_t)(mb) * 1048576)
    // weights (persistent): 0..82 MB
    u16* qkvT_h = (u16*)WSOFF(0);
    u16* qkvT_l = (u16*)WSOFF(3);
    u16* woT_h  = (u16*)WSOFF(6);
    u16* woT_l  = (u16*)WSOFF(8);
    u16* sw1t   = (u16*)WSOFF(10);
    u16* sw2t   = (u16*)WSOFF(14);
    u16* ew1t   = (u16*)WSOFF(18);
    u16* ew2t   = (u16*)WSOFF(50);
    // activations (lifetime-overlapped):
    float* qkv  = (float*)WSOFF(82);
    float* h2f  = (float*)WSOFF(82);
    u16* h_hi   = (u16*)WSOFF(106);
    u16* h_lo   = (u16*)WSOFF(114);
    u16* ao_hi  = (u16*)WSOFF(106);
    u16* ao_lo  = (u16*)WSOFF(114);
    u16* q_hi   = (u16*)WSOFF(122);
    u16* q_lo   = (u16*)WSOFF(130);
    u16* k_hi   = (u16*)WSOFF(138);
    u16* k_lo   = (u16*)WSOFF(140);
    u16* vT_hi  = (u16*)WSOFF(142);
    u16* vT_lo  = (u16*)WSOFF(144);
    float* x1   = (float*)WSOFF(146);   // written after atcomb consumed pacc
    u16* h2b    = (u16*)WSOFF(162);
    u16* midb   = (u16*)WSOFF(170);
    u16* hmidb  = (u16*)WSOFF(122);
    float* eoutb = (float*)WSOFF(154);
    float* pacc = (float*)WSOFF(146);   // 2 x 16 MB (146..178), live mattn->atcomb only
    float* pl   = (float*)WSOFF(178);   // 512 KB   (178..178.5)
    int* meta0  = (int*)WSOFF(186);
    int*   top2i  = meta0;
    float* top2w  = (float*)(meta0 + 8192);
    int*   counts = meta0 + 16384;
    int*   cursor = meta0 + 16392;
    int*   segs   = meta0 + 16400;
    int*   list   = meta0 + 16416;
    float* wslot  = (float*)(meta0 + 16416 + 8192);
    int*   slot_of = meta0 + 16416 + 16384;
    float* ropetab = (float*)WSOFF(190);

    // ---- weight prep + rope table ----
    ropetab_k<<<256, 256, 0, stream>>>(ropetab);
    tcast2_k<<<dim3(32, 32), 256, 0, stream>>>(wq, qkvT_h, qkvT_l, DM, 1024);
    tcast2_k<<<dim3(8, 32), 256, 0, stream>>>(wk, qkvT_h + 1024 * 1024, qkvT_l + 1024 * 1024, DM, 256);
    tcast2_k<<<dim3(8, 32), 256, 0, stream>>>(wv, qkvT_h + 1280 * 1024, qkvT_l + 1280 * 1024, DM, 256);
    tcast2_k<<<dim3(32, 32), 256, 0, stream>>>(wo, woT_h, woT_l, DM, DM);
    tcast_k<<<dim3(NFF / 32, DM / 32, 1), 256, 0, stream>>>(sw1, sw1t, DM, NFF);
    tcast_k<<<dim3(DM / 32, NFF / 32, 1), 256, 0, stream>>>(sw2, sw2t, NFF, DM);
    tcast_k<<<dim3(NFF / 32, DM / 32, NE), 256, 0, stream>>>(ew1, ew1t, DM, NFF);
    tcast_k<<<dim3(DM / 32, NFF / 32, NE), 256, 0, stream>>>(ew2, ew2t, NFF, DM);

    // 1. h = rmsnorm(x) -> hi/lo split
    rmsnorm2_k<0><<<NTOK, 256, 0, stream>>>(x, anw, h_hi, h_lo, nullptr);
    // 2. fused QKV projection (split MFMA) -> qkv f32
    sgemm_k<0><<<dim3(QKVN / 128, NTOK / 128), 256, 0, stream>>>(
        h_hi, h_lo, qkvT_h, qkvT_l, nullptr, qkv, NTOK, QKVN, DM);
    // 3. fused RoPE + split for q,k; V transpose+split
    rope_split_k<<<2048, 256, 0, stream>>>(qkv, ropetab, 0, 1024, q_hi, q_lo);
    rope_split_k<<<512, 256, 0, stream>>>(qkv, ropetab, 1024, 256, k_hi, k_lo);
    vtrans_k<<<dim3(8, 128), 256, 0, stream>>>(qkv, vT_hi, vT_lo);
    // 4. attention: KV-split partials -> combine -> ao hi/lo
    mattn_k<<<dim3(16, 32, 2), 256, 0, stream>>>(q_hi, q_lo, k_hi, k_lo, vT_hi, vT_lo, pacc, pl);
    atcomb_k<<<NTOK, 256, 0, stream>>>(pacc, pl, ao_hi, ao_lo);
    // 5. x1 = ao @ wo + x
    sgemm_k<2><<<dim3(DM / 128, NTOK / 128), 256, 0, stream>>>(
        ao_hi, ao_lo, woT_h, woT_l, x, x1, NTOK, DM, DM);
    // 6. h2 = rmsnorm(x1) -> f32 (gate) + bf16 (MoE)
    rmsnorm2_k<1><<<NTOK, 256, 0, stream>>>(x1, fnw, h2b, nullptr, h2f);
    // 7. gate + routing
    zero16_k<<<1, 64, 0, stream>>>(counts);
    gate_k<<<NTOK, 64, 0, stream>>>(h2f, gw, gb, top2i, top2w, counts);
    scan_k<<<1, 1, 0, stream>>>(counts, segs);
    scatter_k<<<32, 256, 0, stream>>>(top2i, top2w, segs, cursor, list, wslot, slot_of);
    // 8. shared expert
    mgemm_k<1, 0, 0><<<dim3(NFF / 128, NTOK / 128, 1), 256, 0, stream>>>(
        h2b, sw1t, nullptr, nullptr, nullptr, nullptr, nullptr, midb, NTOK, NFF, DM);
    mgemm_k<2, 0, 0><<<dim3(DM / 128, NTOK / 128, 1), 256, 0, stream>>>(
        midb, sw2t, x1, nullptr, nullptr, nullptr, out, nullptr, NTOK, DM, NFF);
    // 9. routed experts
    mgemm_k<1, 1, 1><<<dim3(NFF / 128, NTOK / 128, NE), 256, 0, stream>>>(
        h2b, ew1t, nullptr, nullptr, list, segs, nullptr, hmidb, NTOK, NFF, DM);
    mgemm_k<3, 1, 0><<<dim3(DM / 128, NTOK / 128, NE), 256, 0, stream>>>(
        hmidb, ew2t, nullptr, wslot, nullptr, segs, eoutb, nullptr, 2 * NTOK, DM, NFF);
    combine_k<<<NTOK, 256, 0, stream>>>(eoutb, slot_of, out);
#undef WSOFF
}